// Round 1
// baseline (1035.122 us; speedup 1.0000x reference)
//
#include <hip/hip_runtime.h>
#include <hip/hip_bf16.h>
#include <math.h>

#define TT 1024
#define KK 128
#define BB 512
#define MINV -100000.0f

// One block per batch row. 128 threads (2 waves); thread j owns output tag "to"=j.
// E[to][frm] = exp(trans[to][frm]) kept in registers (128 VGPRs/thread).
// Per step: m = max(alpha); p = exp(alpha-m) -> LDS (double-buffered);
//           s[to] = sum_frm E[to][frm]*p[frm]; alpha[to] = log(s)+m+feat[t][to].
__global__ __launch_bounds__(128, 1)
void crf_fwd_kernel(const float* __restrict__ feats,
                    const float* __restrict__ trans,
                    float* __restrict__ out)
{
    const int b    = blockIdx.x;
    const int to   = threadIdx.x;   // 0..127
    const int wv   = to >> 6;       // wave 0/1
    const int lane = to & 63;

    __shared__ __align__(16) float p_lds[2][KK];
    __shared__ float wred[2][2];
    __shared__ float sred[2];

    // ---- Stage E row into registers: E[frm] = exp(trans[to][frm]) ----
    float E[KK];
    {
        const float4* tr = reinterpret_cast<const float4*>(trans + to * KK);
        #pragma unroll
        for (int f4 = 0; f4 < KK / 4; ++f4) {
            float4 v = tr[f4];
            E[4 * f4 + 0] = __expf(v.x);
            E[4 * f4 + 1] = __expf(v.y);
            E[4 * f4 + 2] = __expf(v.z);
            E[4 * f4 + 3] = __expf(v.w);
        }
    }
    // trans[END][to] for the final logsumexp
    const float tEnd = trans[(KK - 2) * KK + to];

    const float* fb = feats + (size_t)b * TT * KK + to;
    float fcur = fb[0];

    // init alpha: MIN_VAL everywhere except START (= K-1)
    float a = (to == KK - 1) ? 0.0f : MINV;

    for (int t = 0; t < TT; ++t) {
        const int buf = t & 1;

        // prefetch next step's feat early (hide HBM latency under compute)
        float fnext = 0.0f;
        if (t + 1 < TT) fnext = fb[(size_t)(t + 1) * KK];

        // ---- m = max over all 128 alpha ----
        float wm = a;
        #pragma unroll
        for (int s = 32; s >= 1; s >>= 1)
            wm = fmaxf(wm, __shfl_xor(wm, s, 64));
        if (lane == 0) wred[buf][wv] = wm;
        __syncthreads();
        const float m = fmaxf(wred[buf][0], wred[buf][1]);

        // ---- p = exp(alpha - m) into LDS ----
        p_lds[buf][to] = __expf(a - m);
        __syncthreads();

        // ---- s[to] = sum_frm E[frm] * p[frm] (uniform b128 broadcast reads) ----
        const float4* p4 = reinterpret_cast<const float4*>(p_lds[buf]);
        float s0 = 0.f, s1 = 0.f, s2 = 0.f, s3 = 0.f;
        #pragma unroll
        for (int f4 = 0; f4 < KK / 4; ++f4) {
            float4 pv = p4[f4];
            s0 = fmaf(E[4 * f4 + 0], pv.x, s0);
            s1 = fmaf(E[4 * f4 + 1], pv.y, s1);
            s2 = fmaf(E[4 * f4 + 2], pv.z, s2);
            s3 = fmaf(E[4 * f4 + 3], pv.w, s3);
        }
        const float s = (s0 + s1) + (s2 + s3);

        a = __logf(s) + m + fcur;   // log(0) -> -inf for START row: harmless, exp(-inf)=0
        fcur = fnext;
    }

    // ---- out[b] = logsumexp_to(alpha[to] + trans[END][to]) ----
    const float fin = a + tEnd;
    float wm = fin;
    #pragma unroll
    for (int s = 32; s >= 1; s >>= 1)
        wm = fmaxf(wm, __shfl_xor(wm, s, 64));
    if (lane == 0) wred[0][wv] = wm;
    __syncthreads();
    const float M = fmaxf(wred[0][0], wred[0][1]);

    float e = __expf(fin - M);
    #pragma unroll
    for (int s = 32; s >= 1; s >>= 1)
        e += __shfl_xor(e, s, 64);
    if (lane == 0) sred[wv] = e;
    __syncthreads();
    if (to == 0) out[b] = M + __logf(sred[0] + sred[1]);
}

extern "C" void kernel_launch(void* const* d_in, const int* in_sizes, int n_in,
                              void* d_out, int out_size, void* d_ws, size_t ws_size,
                              hipStream_t stream) {
    const float* feats = (const float*)d_in[0];  // [B, T, K] f32
    const float* trans = (const float*)d_in[1];  // [K, K] f32
    float* out = (float*)d_out;                  // [B] f32

    crf_fwd_kernel<<<BB, KK, 0, stream>>>(feats, trans, out);
}

// Round 2
// 619.482 us; speedup vs baseline: 1.6709x; 1.6709x over previous
//
#include <hip/hip_runtime.h>
#include <hip/hip_bf16.h>
#include <math.h>

#define TT 1024
#define KK 128
#define BB 512
#define MINV -100000.0f

typedef float v2f __attribute__((ext_vector_type(2)));

// One block per batch row, 128 threads (2 waves), thread j owns tag "to"=j.
// E[to][frm] = exp(trans[to][frm]) in registers. Per step (ONE barrier):
//   p[to] = exp(a - m) -> LDS ; thread0 publishes a (becomes next step's m)
//   barrier
//   s[to] = sum_frm E*p  (v_pk_fma_f32) ; a = log(s) + m + feat[t][to]
// m is a stale-by-one approximate max: exp args stay within ~e^18, fp32-safe,
// and m cancels exactly in log(s)+m so the result is exact.
__global__ __launch_bounds__(128, 1)
void crf_fwd_kernel(const float* __restrict__ feats,
                    const float* __restrict__ trans,
                    float* __restrict__ out)
{
    const int b    = blockIdx.x;
    const int to   = threadIdx.x;   // 0..127
    const int wv   = to >> 6;
    const int lane = to & 63;

    __shared__ __align__(16) float p_lds[2][KK];
    __shared__ float mslot[2];
    __shared__ float wred[2];
    __shared__ float sred[2];

    // ---- E row in registers as float2 pairs: E2[f][0..1] ----
    v2f E2[KK / 2];
    {
        const float4* tr = reinterpret_cast<const float4*>(trans + to * KK);
        #pragma unroll
        for (int f4 = 0; f4 < KK / 4; ++f4) {
            float4 v = tr[f4];
            E2[2 * f4 + 0] = v2f{__expf(v.x), __expf(v.y)};
            E2[2 * f4 + 1] = v2f{__expf(v.z), __expf(v.w)};
        }
    }
    const float tEnd = trans[(KK - 2) * KK + to];

    // 2-deep feat prefetch (4B/thread/step, coalesced 512B/block)
    const float* fp = feats + (size_t)b * TT * KK + to;
    float f0 = fp[0];
    float f1 = fp[KK];
    fp += 2 * KK;

    float a = (to == KK - 1) ? 0.0f : MINV;  // alpha_0
    float m = 0.0f;                          // exact max of alpha_0

    for (int t = 0; t < TT; ++t) {
        const int buf = t & 1;

        // prefetch feat[t+2]
        float f2 = 0.0f;
        if (t + 2 < TT) f2 = *fp;
        fp += KK;

        if (to == 0) mslot[buf] = a;        // publish alpha_t[0] = next m
        p_lds[buf][to] = __expf(a - m);
        __syncthreads();                    // the ONE barrier per step

        // next step's offset; alpha_0[0] = MINV is useless, use 0 (alpha_1 is O(10))
        const float m_next = (t == 0) ? 0.0f : mslot[buf];

        // ---- s = sum_frm E[frm]*p[frm], packed fp32, 4 accum chains ----
        const float4* p4 = reinterpret_cast<const float4*>(p_lds[buf]);
        v2f acc0 = {0.f, 0.f}, acc1 = {0.f, 0.f};
        v2f acc2 = {0.f, 0.f}, acc3 = {0.f, 0.f};
        #pragma unroll
        for (int f4 = 0; f4 < KK / 4; f4 += 2) {
            float4 pa = p4[f4];
            float4 pb = p4[f4 + 1];
            acc0 = __builtin_elementwise_fma(E2[2 * f4 + 0], v2f{pa.x, pa.y}, acc0);
            acc1 = __builtin_elementwise_fma(E2[2 * f4 + 1], v2f{pa.z, pa.w}, acc1);
            acc2 = __builtin_elementwise_fma(E2[2 * f4 + 2], v2f{pb.x, pb.y}, acc2);
            acc3 = __builtin_elementwise_fma(E2[2 * f4 + 3], v2f{pb.z, pb.w}, acc3);
        }
        v2f accA = acc0 + acc1;
        v2f accB = acc2 + acc3;
        const float s = (accA.x + accA.y) + (accB.x + accB.y);

        a = __logf(s) + m + f0;   // log(0) -> -inf for START tag: propagates as 0-weight
        f0 = f1; f1 = f2;
        m = m_next;
    }

    // ---- out[b] = logsumexp_to(alpha[to] + trans[END][to]) (exact, once) ----
    const float fin = a + tEnd;
    float wm = fin;
    #pragma unroll
    for (int s = 32; s >= 1; s >>= 1)
        wm = fmaxf(wm, __shfl_xor(wm, s, 64));
    if (lane == 0) wred[wv] = wm;
    __syncthreads();
    const float M = fmaxf(wred[0], wred[1]);

    float e = __expf(fin - M);
    #pragma unroll
    for (int s = 32; s >= 1; s >>= 1)
        e += __shfl_xor(e, s, 64);
    if (lane == 0) sred[wv] = e;
    __syncthreads();
    if (to == 0) out[b] = M + __logf(sred[0] + sred[1]);
}

extern "C" void kernel_launch(void* const* d_in, const int* in_sizes, int n_in,
                              void* d_out, int out_size, void* d_ws, size_t ws_size,
                              hipStream_t stream) {
    const float* feats = (const float*)d_in[0];  // [B, T, K] f32
    const float* trans = (const float*)d_in[1];  // [K, K] f32
    float* out = (float*)d_out;                  // [B] f32

    crf_fwd_kernel<<<BB, KK, 0, stream>>>(feats, trans, out);
}